// Round 14
// baseline (153.561 us; speedup 1.0000x reference)
//
#include <hip/hip_runtime.h>
#include <hip/hip_bf16.h>

// Problem constants
#define BB    128
#define C_IN  9
#define T0    2048
#define T1    1024      // after pool1
#define T2    512       // after pool2
#define NN    65536     // B * T2 nodes
#define EE    524288    // edges
#define FEAT  32
#define HID   128
#define OUTC  6
#define CAP   64        // bucket capacity; deg ~ Poisson(8), P(deg>=64) ~ 1e-35

typedef __attribute__((ext_vector_type(8))) short bf16x8;
typedef __attribute__((ext_vector_type(4))) float f32x4;

__device__ __forceinline__ float bf_lo(unsigned u) { return __uint_as_float(u << 16); }
__device__ __forceinline__ float bf_hi(unsigned u) { return __uint_as_float(u & 0xffff0000u); }
__device__ __forceinline__ unsigned short f2bf(float f) {
    unsigned x = __float_as_uint(f);
    return (unsigned short)((x + 0x7fffu + ((x >> 16) & 1u)) >> 16);   // RNE
}
__device__ __forceinline__ float disv(int deg) { return rsqrtf((float)deg + 1.0f); }

// ---------------- zero cnt + W2 transpose/bf16 prep (64 blocks) ------------------------
__global__ __launch_bounds__(256) void k_zw(int4* __restrict__ cnt4,
                                            const float* __restrict__ w2,
                                            unsigned short* __restrict__ wt2) {
    int gid = blockIdx.x * 256 + threadIdx.x;      // 0..16383
    cnt4[gid] = make_int4(0, 0, 0, 0);             // 65536 ints
    int col = gid & 127, k = gid >> 7;
    wt2[col * 128 + k] = f2bf(w2[(size_t)k * 128 + col]);
}

// ---------------- single-pass bucket CSR: cnt[d]++ and bucket[d][pos] = s ---------------
__global__ __launch_bounds__(256) void k_fillB(const int* __restrict__ ei,
                                               int* __restrict__ cnt,
                                               int* __restrict__ bucket) {
    int e = blockIdx.x * 256 + threadIdx.x;
    if (e >= EE) return;
    int s = ei[e];
    int d = ei[EE + e];
    int pos = atomicAdd(&cnt[d], 1);
    if (pos < CAP) bucket[d * CAP + pos] = s;
}

// ---------------- fused conv1+conv2 (LDS-resident h1): x -> nodes_b (bf16, pre-scaled) --
__global__ __launch_bounds__(256) void k_conv12(const float* __restrict__ x,
                                                const float* __restrict__ w1c,
                                                const float* __restrict__ b1c,
                                                const float* __restrict__ w2c,
                                                const float* __restrict__ b2c,
                                                const int* __restrict__ cnt,
                                                unsigned short* __restrict__ nodes_b) {
    __shared__ float sx[C_IN][272];      // 268 used
    __shared__ float sh[16][136];        // 132 used (h1 tile incl. halo)
    __shared__ float swt1[45 * 16];
    __shared__ float swt2[80 * 32];
    int b   = blockIdx.x >> 3;
    int qt  = blockIdx.x & 7;
    int tid = threadIdx.x;
    int t1lo = qt * 128 - 2;
    int gxb  = 2 * t1lo - 2;             // x base

    const float* xb = x + (size_t)b * C_IN * T0;
    #pragma unroll
    for (int c = 0; c < C_IN; ++c)
        for (int i = tid; i < 268; i += 256) {
            int g = gxb + i;
            sx[c][i] = ((unsigned)g < T0) ? xb[c * T0 + g] : 0.f;
        }
    for (int idx = tid; idx < 720; idx += 256) {
        int o = idx & 15, ck = idx >> 4;
        swt1[ck * 16 + o] = w1c[o * 45 + ck];
    }
    for (int idx = tid; idx < 2560; idx += 256) {
        int o = idx & 31, ck = idx >> 5;
        swt2[ck * 32 + o] = w2c[o * 80 + ck];
    }
    __syncthreads();

    // ---- conv1 + relu + pool2 -> sh[16][132] ----
    {
        int o = tid >> 4, sub = tid & 15;
        float A0[9], A1[9];
        #pragma unroll
        for (int ii = 0; ii < 9; ++ii) { A0[ii] = 0.f; A1[ii] = 0.f; }
        #pragma unroll
        for (int c = 0; c < C_IN; ++c) {
            float wt[5];
            #pragma unroll
            for (int k = 0; k < 5; ++k) wt[k] = swt1[(c * 5 + k) * 16 + o];
            #pragma unroll
            for (int ii = 0; ii < 9; ++ii) {
                int pos = sub + ii * 16;
                if (pos < 132) {
                    const float* sp = &sx[c][2 * pos];
                    float2 p0 = *(const float2*)(sp);
                    float2 p1 = *(const float2*)(sp + 2);
                    float2 p2 = *(const float2*)(sp + 4);
                    A0[ii] += wt[0]*p0.x + wt[1]*p0.y + wt[2]*p1.x + wt[3]*p1.y + wt[4]*p2.x;
                    A1[ii] += wt[0]*p0.y + wt[1]*p1.x + wt[2]*p1.y + wt[3]*p2.x + wt[4]*p2.y;
                }
            }
        }
        float bo = b1c[o];
        #pragma unroll
        for (int ii = 0; ii < 9; ++ii) {
            int pos = sub + ii * 16;
            if (pos < 132) {
                int t = t1lo + pos;
                float h = fmaxf(fmaxf(A0[ii], A1[ii]) + bo, 0.f);
                sh[o][pos] = ((unsigned)t < T1) ? h : 0.f;   // zero-pad outside T1
            }
        }
    }
    __syncthreads();

    // ---- conv2 + relu + pool2 + dis-scale -> nodes_b (bf16) ----
    int lane = tid & 63;
    int wv   = tid >> 6;
    int o    = lane & 31;
    int slot = lane >> 5;
    int ttl0 = wv * 16 + slot * 8;

    float acc[16];
    #pragma unroll
    for (int i = 0; i < 16; ++i) acc[i] = 0.f;

    #pragma unroll
    for (int c = 0; c < 16; ++c) {
        float wt[5];
        #pragma unroll
        for (int k = 0; k < 5; ++k) wt[k] = swt2[(c * 5 + k) * 32 + o];
        #pragma unroll
        for (int cb = 0; cb < 2; ++cb) {
            int Pb = 2 * ttl0 + 8 * cb;
            float4 i0 = *(const float4*)&sh[c][Pb];
            float4 i1 = *(const float4*)&sh[c][Pb + 4];
            float4 i2 = *(const float4*)&sh[c][Pb + 8];
            float in[12] = {i0.x,i0.y,i0.z,i0.w, i1.x,i1.y,i1.z,i1.w, i2.x,i2.y,i2.z,i2.w};
            #pragma unroll
            for (int q = 0; q < 8; ++q) {
                float s = acc[cb * 8 + q];
                #pragma unroll
                for (int k = 0; k < 5; ++k) s += wt[k] * in[q + k];
                acc[cb * 8 + q] = s;
            }
        }
    }

    float bi = b2c[o];
    int node0 = b * T2 + qt * 64 + ttl0;
    size_t nbase = (size_t)node0 * FEAT + o;
    #pragma unroll
    for (int cb = 0; cb < 2; ++cb)
        #pragma unroll
        for (int jj = 0; jj < 4; ++jj) {
            int node = node0 + cb * 4 + jj;
            float v = fmaxf(fmaxf(acc[cb*8+2*jj], acc[cb*8+2*jj+1]) + bi, 0.f);
            nodes_b[nbase + (size_t)(cb * 4 + jj) * FEAT] = f2bf(v * disv(cnt[node]));
        }
}

// ---------------- gather1 (bf16 in, bf16 out): aggN_b[d] = bf16(dis[d]*(nb[d]+Σnb[src]))
__global__ __launch_bounds__(256) void k_gather1(const unsigned short* __restrict__ nodes_b,
                                                 const int* __restrict__ cnt,
                                                 const int* __restrict__ bucket,
                                                 unsigned int* __restrict__ aggN_b) {
    int t = blockIdx.x * 256 + threadIdx.x;
    int node = t >> 3;                    // 8 lanes per node, 8B bf16 each
    if (node >= NN) return;
    int lane = t & 7;
    int deg = cnt[node];
    const int* bk = bucket + node * CAP;
    const uint2* nb = (const uint2*)nodes_b;
    uint2 q = nb[(size_t)node * 8 + lane];
    float a0 = bf_lo(q.x), a1 = bf_hi(q.x), a2 = bf_lo(q.y), a3 = bf_hi(q.y);
    for (int j = 0; j < deg; ++j) {
        int s = bk[j];
        uint2 p = nb[(size_t)s * 8 + lane];
        a0 += bf_lo(p.x); a1 += bf_hi(p.x); a2 += bf_lo(p.y); a3 += bf_hi(p.y);
    }
    float dd = disv(deg);
    uint2 r;
    r.x = (unsigned)f2bf(a0 * dd) | ((unsigned)f2bf(a1 * dd) << 16);
    r.y = (unsigned)f2bf(a2 * dd) | ((unsigned)f2bf(a3 * dd) << 16);
    ((uint2*)aggN_b)[(size_t)node * 8 + lane] = r;
}

// ---------------- fused GCN transform (BM=64): L1 fp32 GEMM + relu/bias + L2 MFMA ------
// xws2[n] = bf16( (relu(aggN[n]@W1 + b1) @ W2) * dis[n] ), per 64-row block.
// W2 fragments read directly from global (L2-resident 32KB) — no sW stage, ~25KB LDS.
__global__ __launch_bounds__(256) void k_fused(const unsigned int* __restrict__ aggN_b,
                                               const float* __restrict__ w1,     // [32][128]
                                               const unsigned short* __restrict__ wt2, // [col][k] bf16
                                               const float* __restrict__ b1,
                                               const int* __restrict__ cnt,
                                               unsigned short* __restrict__ xws2) {
    __shared__ union {
        struct { float an[32][68]; float w1s[32][132]; } p1;    // 25.6 KB
        short sa[64 * 128];                                     // 16 KB, swizzled bf16 A
    } u;

    int tid = threadIdx.x;
    int rowBase = blockIdx.x * 64;

    // stage aggN block (bf16 -> fp32, k-major) + W1
    {
        int row = tid >> 2;               // 0..63
        int qq  = tid & 3;                // 0..3 -> 8 bf16 each
        uint2 v0 = *(const uint2*)(aggN_b + (size_t)(rowBase + row) * 8 + qq * 2);
        uint2 v1 = *(const uint2*)(aggN_b + (size_t)(rowBase + row) * 8 + qq * 2 + 1);
        // note: aggN_b is uint per 2 bf16; row = 16 uints; qq*4 .. qq*4+3
        const unsigned* ap = aggN_b + (size_t)(rowBase + row) * 16 + qq * 4;
        unsigned w0 = ap[0], w1u = ap[1], w2u = ap[2], w3 = ap[3];
        int k0 = qq * 8;
        u.p1.an[k0 + 0][row] = bf_lo(w0); u.p1.an[k0 + 1][row] = bf_hi(w0);
        u.p1.an[k0 + 2][row] = bf_lo(w1u); u.p1.an[k0 + 3][row] = bf_hi(w1u);
        u.p1.an[k0 + 4][row] = bf_lo(w2u); u.p1.an[k0 + 5][row] = bf_hi(w2u);
        u.p1.an[k0 + 6][row] = bf_lo(w3); u.p1.an[k0 + 7][row] = bf_hi(w3);
        (void)v0; (void)v1;
        #pragma unroll
        for (int it = 0; it < 4; ++it) {
            int i = tid + it * 256;       // 0..1023 float4s over [32][128]
            int k  = i >> 5;
            int c4 = (i & 31) * 4;
            *(float4*)&u.p1.w1s[k][c4] = *(const float4*)(w1 + k * HID + c4);
        }
    }
    __syncthreads();

    // ---- layer-1 fp32 GEMM: 4x8 per thread over [64][128] ----
    int tr = tid >> 4, tc = tid & 15;
    float acc[4][8];
    #pragma unroll
    for (int i = 0; i < 4; ++i)
        #pragma unroll
        for (int j = 0; j < 8; ++j) acc[i][j] = 0.f;

    #pragma unroll 8
    for (int k = 0; k < FEAT; ++k) {
        float4 a0 = *(const float4*)&u.p1.an[k][tr * 4];
        float4 b0 = *(const float4*)&u.p1.w1s[k][tc * 8];
        float4 b1v = *(const float4*)&u.p1.w1s[k][tc * 8 + 4];
        float av[4] = {a0.x, a0.y, a0.z, a0.w};
        float bv[8] = {b0.x, b0.y, b0.z, b0.w, b1v.x, b1v.y, b1v.z, b1v.w};
        #pragma unroll
        for (int i = 0; i < 4; ++i)
            #pragma unroll
            for (int j = 0; j < 8; ++j) acc[i][j] += av[i] * bv[j];
    }
    __syncthreads();   // phase-1 LDS dead; safe to overlay with sa

    // ---- bias + relu + bf16 pack into swizzled A-tile ----
    {
        float4 bb0 = *(const float4*)(b1 + tc * 8);
        float4 bb1 = *(const float4*)(b1 + tc * 8 + 4);
        float bv[8] = {bb0.x, bb0.y, bb0.z, bb0.w, bb1.x, bb1.y, bb1.z, bb1.w};
        #pragma unroll
        for (int i = 0; i < 4; ++i) {
            int row = tr * 4 + i;
            unsigned short us[8];
            #pragma unroll
            for (int j = 0; j < 8; ++j) us[j] = f2bf(fmaxf(acc[i][j] + bv[j], 0.f));
            uint4 pv;
            pv.x = (unsigned)us[0] | ((unsigned)us[1] << 16);
            pv.y = (unsigned)us[2] | ((unsigned)us[3] << 16);
            pv.z = (unsigned)us[4] | ((unsigned)us[5] << 16);
            pv.w = (unsigned)us[6] | ((unsigned)us[7] << 16);
            *(uint4*)&u.sa[row * 128 + ((tc * 8) ^ ((row & 7) << 3))] = pv;
        }
    }
    __syncthreads();

    // ---- layer-2 MFMA bf16: wave wv owns 16-row tile, W2 frags from global ----
    int lane = tid & 63;
    int wv   = tid >> 6;
    int lrow = lane & 15;
    int kg   = lane >> 4;                // k-group 0..3

    f32x4 zero = {0.f, 0.f, 0.f, 0.f};
    f32x4 macc[8];
    #pragma unroll
    for (int ct = 0; ct < 8; ++ct) macc[ct] = zero;

    int r = wv * 16 + lrow;
    #pragma unroll
    for (int ks = 0; ks < 4; ++ks) {
        int kb8 = ks * 4 + kg;           // 8-bf16 chunk index along k
        bf16x8 af = *(const bf16x8*)&u.sa[r * 128 + ((kb8 * 8) ^ ((r & 7) << 3))];
        #pragma unroll
        for (int ct = 0; ct < 8; ++ct) {
            int c = ct * 16 + lrow;
            bf16x8 bfr = *(const bf16x8*)(wt2 + (size_t)c * 128 + kb8 * 8);
            macc[ct] = __builtin_amdgcn_mfma_f32_16x16x32_bf16(af, bfr, macc[ct], 0, 0, 0);
        }
    }

    // epilogue: D layout col=lane&15, row=(lane>>4)*4+reg
    int r0 = rowBase + wv * 16 + kg * 4;
    #pragma unroll
    for (int q = 0; q < 4; ++q) {
        int grow = r0 + q;
        float d = disv(cnt[grow]);
        unsigned short* op = xws2 + (size_t)grow * HID + lrow;
        #pragma unroll
        for (int ct = 0; ct < 8; ++ct)
            op[ct * 16] = f2bf(macc[ct][q] * d);
    }
}

// ---------------- gather2 + fused pool: partial[blk][f] = sum_nodes relu(agg2+b2) ------
__global__ __launch_bounds__(256) void k_gather2(const unsigned short* __restrict__ xws2,
                                                 const int* __restrict__ cnt,
                                                 const int* __restrict__ bucket,
                                                 const float* __restrict__ b2,
                                                 float* __restrict__ partial) {
    __shared__ float sred[16][136];
    int t = blockIdx.x * 256 + threadIdx.x;
    int node = t >> 4;                    // 16 lanes per node (8 bf16 each)
    int lane = t & 15;
    int nloc = threadIdx.x >> 4;
    int deg = cnt[node];
    const int* bk = bucket + node * CAP;
    const uint4* xv = (const uint4*)xws2;
    uint4 q = xv[(size_t)node * 16 + lane];
    float a0 = bf_lo(q.x), a1 = bf_hi(q.x), a2 = bf_lo(q.y), a3 = bf_hi(q.y);
    float a4 = bf_lo(q.z), a5 = bf_hi(q.z), a6 = bf_lo(q.w), a7 = bf_hi(q.w);
    for (int j = 0; j < deg; ++j) {
        int s = bk[j];
        uint4 p = xv[(size_t)s * 16 + lane];
        a0 += bf_lo(p.x); a1 += bf_hi(p.x); a2 += bf_lo(p.y); a3 += bf_hi(p.y);
        a4 += bf_lo(p.z); a5 += bf_hi(p.z); a6 += bf_lo(p.w); a7 += bf_hi(p.w);
    }
    float dd = disv(deg);
    float4 pb0 = *(const float4*)(b2 + lane * 8);
    float4 pb1 = *(const float4*)(b2 + lane * 8 + 4);
    float* sp = &sred[nloc][lane * 8];
    sp[0] = fmaxf(a0 * dd + pb0.x, 0.f);
    sp[1] = fmaxf(a1 * dd + pb0.y, 0.f);
    sp[2] = fmaxf(a2 * dd + pb0.z, 0.f);
    sp[3] = fmaxf(a3 * dd + pb0.w, 0.f);
    sp[4] = fmaxf(a4 * dd + pb1.x, 0.f);
    sp[5] = fmaxf(a5 * dd + pb1.y, 0.f);
    sp[6] = fmaxf(a6 * dd + pb1.z, 0.f);
    sp[7] = fmaxf(a7 * dd + pb1.w, 0.f);
    __syncthreads();
    int f = threadIdx.x;
    if (f < 128) {
        float s = 0.f;
        #pragma unroll
        for (int n = 0; n < 16; ++n) s += sred[n][f];
        partial[(size_t)blockIdx.x * HID + f] = s;
    }
}

// ---------------- classifier: out[b][f] = mean @ cls_w + cls_b -------------------------
__global__ __launch_bounds__(128) void k_cls(const float* __restrict__ partial,
                                             const float* __restrict__ clsw,
                                             const float* __restrict__ clsb,
                                             float* __restrict__ out) {
    __shared__ float pooled[HID];
    int b = blockIdx.x;
    int f = threadIdx.x;
    const float* p = partial + (size_t)b * 32 * HID + f;
    float s = 0.f;
    #pragma unroll 8
    for (int c = 0; c < 32; ++c) s += p[c * HID];
    pooled[f] = s;
    __syncthreads();
    if (f < OUTC) {
        float acc = 0.f;
        #pragma unroll 8
        for (int k = 0; k < HID; ++k) acc += pooled[k] * clsw[k * OUTC + f];
        out[b * OUTC + f] = acc * (1.0f / (float)T2) + clsb[f];
    }
}

extern "C" void kernel_launch(void* const* d_in, const int* in_sizes, int n_in,
                              void* d_out, int out_size, void* d_ws, size_t ws_size,
                              hipStream_t stream) {
    const float* x    = (const float*)d_in[0];
    const int*   ei   = (const int*)d_in[1];
    const float* c1w  = (const float*)d_in[2];
    const float* c1b  = (const float*)d_in[3];
    const float* c2w  = (const float*)d_in[4];
    const float* c2b  = (const float*)d_in[5];
    const float* g1w  = (const float*)d_in[6];
    const float* g1b  = (const float*)d_in[7];
    const float* g2w  = (const float*)d_in[8];
    const float* g2b  = (const float*)d_in[9];
    const float* clsw = (const float*)d_in[10];
    const float* clsb = (const float*)d_in[11];
    float* out = (float*)d_out;

    float* ws = (float*)d_ws;
    unsigned int* aggN_b = (unsigned int*)ws;                  // N*16 uint = 4 MB
    float* partial  = ws + 1048576;                            // 4096*128 floats
    unsigned short* wt2 = (unsigned short*)(ws + 1572864);     // 16384 bf16
    unsigned short* nodes_b = (unsigned short*)(ws + 1581056); // N*32 bf16 = 4 MB
    unsigned short* xws2 = (unsigned short*)(ws + 2629632);    // N*128 bf16 = 16 MB
    int* cnt        = (int*)(ws + 6823936);                    // 65536 ints
    int* bucket     = (int*)(ws + 6889472);                    // NN*CAP ints = 16 MB
    // total ~44 MB

    // single-pass bucket CSR build (cnt zeroed + W2 prep, then deg+fill fused)
    k_zw   <<<64, 256, 0, stream>>>((int4*)cnt, g2w, wt2);
    k_fillB<<<EE / 256, 256, 0, stream>>>(ei, cnt, bucket);

    // fused temporal conv stack (h1 LDS-resident), bf16 pre-scaled nodes
    k_conv12<<<BB * 8, 256, 0, stream>>>(x, c1w, c1b, c2w, c2b, cnt, nodes_b);

    // GCN layer 1 aggregation (standalone, high occupancy, bf16 in/out)
    k_gather1<<<(NN * 8) / 256, 256, 0, stream>>>(nodes_b, cnt, bucket, aggN_b);

    // fused GCN transform: L1 fp32 + relu/bias + L2 MFMA bf16 (BM=64, W2 from L2)
    k_fused<<<NN / 64, 256, 0, stream>>>(aggN_b, g1w, wt2, g1b, cnt, xws2);

    // layer-2 aggregation with fused mean-pool partials
    k_gather2<<<(NN * 16) / 256, 256, 0, stream>>>(xws2, cnt, bucket, g2b, partial);

    // classifier
    k_cls<<<BB, 128, 0, stream>>>(partial, clsw, clsb, out);
}

// Round 17
// 129.620 us; speedup vs baseline: 1.1847x; 1.1847x over previous
//
#include <hip/hip_runtime.h>
#include <hip/hip_bf16.h>

// Problem constants
#define BB    128
#define C_IN  9
#define T0    2048
#define T1    1024      // after pool1
#define T2    512       // after pool2
#define NN    65536     // B * T2 nodes
#define EE    524288    // edges
#define FEAT  32
#define HID   128
#define OUTC  6
#define CAP   64        // bucket capacity; deg ~ Poisson(8), P(deg>=64) ~ 1e-35

typedef __attribute__((ext_vector_type(8))) short bf16x8;
typedef __attribute__((ext_vector_type(4))) float f32x4;

__device__ __forceinline__ float bf_lo(unsigned u) { return __uint_as_float(u << 16); }
__device__ __forceinline__ float bf_hi(unsigned u) { return __uint_as_float(u & 0xffff0000u); }
__device__ __forceinline__ unsigned short f2bf(float f) {
    unsigned x = __float_as_uint(f);
    return (unsigned short)((x + 0x7fffu + ((x >> 16) & 1u)) >> 16);   // RNE
}
__device__ __forceinline__ float disv(int deg) { return rsqrtf((float)deg + 1.0f); }
__device__ __forceinline__ unsigned char f2fp8(float v) {
    int pk = __builtin_amdgcn_cvt_pk_fp8_f32(v, v, 0, false);   // HW RNE, OCP e4m3 on gfx950
    return (unsigned char)(pk & 0xff);
}
// unpack 4 fp8 bytes of word w (selector must be a literal)
__device__ __forceinline__ void fp8x4_to_f32(unsigned w, float* f) {
    f[0] = __builtin_amdgcn_cvt_f32_fp8(w, 0);
    f[1] = __builtin_amdgcn_cvt_f32_fp8(w, 1);
    f[2] = __builtin_amdgcn_cvt_f32_fp8(w, 2);
    f[3] = __builtin_amdgcn_cvt_f32_fp8(w, 3);
}
__device__ __forceinline__ void fp8x4_acc_f32(unsigned w, float* f) {
    f[0] += __builtin_amdgcn_cvt_f32_fp8(w, 0);
    f[1] += __builtin_amdgcn_cvt_f32_fp8(w, 1);
    f[2] += __builtin_amdgcn_cvt_f32_fp8(w, 2);
    f[3] += __builtin_amdgcn_cvt_f32_fp8(w, 3);
}

// ---------------- zero cnt + W2 transpose/bf16 prep (64 blocks) ------------------------
__global__ __launch_bounds__(256) void k_zw(int4* __restrict__ cnt4,
                                            const float* __restrict__ w2,
                                            unsigned short* __restrict__ wt2) {
    int gid = blockIdx.x * 256 + threadIdx.x;      // 0..16383
    cnt4[gid] = make_int4(0, 0, 0, 0);             // 65536 ints
    int col = gid & 127, k = gid >> 7;
    wt2[col * 128 + k] = f2bf(w2[(size_t)k * 128 + col]);
}

// ---------------- single-pass bucket CSR: cnt[d]++ and bucket[d][pos] = s ---------------
__global__ __launch_bounds__(256) void k_fillB(const int* __restrict__ ei,
                                               int* __restrict__ cnt,
                                               int* __restrict__ bucket) {
    int e = blockIdx.x * 256 + threadIdx.x;
    if (e >= EE) return;
    int s = ei[e];
    int d = ei[EE + e];
    int pos = atomicAdd(&cnt[d], 1);
    if (pos < CAP) bucket[d * CAP + pos] = s;
}

// ---------------- fused conv1+conv2 (LDS-resident h1): x -> nodes_b (bf16, pre-scaled) --
__global__ __launch_bounds__(256) void k_conv12(const float* __restrict__ x,
                                                const float* __restrict__ w1c,
                                                const float* __restrict__ b1c,
                                                const float* __restrict__ w2c,
                                                const float* __restrict__ b2c,
                                                const int* __restrict__ cnt,
                                                unsigned short* __restrict__ nodes_b) {
    __shared__ float sx[C_IN][272];      // 268 used
    __shared__ float sh[16][136];        // 132 used (h1 tile incl. halo)
    __shared__ float swt1[45 * 16];
    __shared__ float swt2[80 * 32];
    int b   = blockIdx.x >> 3;
    int qt  = blockIdx.x & 7;
    int tid = threadIdx.x;
    int t1lo = qt * 128 - 2;
    int gxb  = 2 * t1lo - 2;             // x base

    const float* xb = x + (size_t)b * C_IN * T0;
    #pragma unroll
    for (int c = 0; c < C_IN; ++c)
        for (int i = tid; i < 268; i += 256) {
            int g = gxb + i;
            sx[c][i] = ((unsigned)g < T0) ? xb[c * T0 + g] : 0.f;
        }
    for (int idx = tid; idx < 720; idx += 256) {
        int o = idx & 15, ck = idx >> 4;
        swt1[ck * 16 + o] = w1c[o * 45 + ck];
    }
    for (int idx = tid; idx < 2560; idx += 256) {
        int o = idx & 31, ck = idx >> 5;
        swt2[ck * 32 + o] = w2c[o * 80 + ck];
    }
    __syncthreads();

    // ---- conv1 + relu + pool2 -> sh[16][132] ----
    {
        int o = tid >> 4, sub = tid & 15;
        float A0[9], A1[9];
        #pragma unroll
        for (int ii = 0; ii < 9; ++ii) { A0[ii] = 0.f; A1[ii] = 0.f; }
        #pragma unroll
        for (int c = 0; c < C_IN; ++c) {
            float wt[5];
            #pragma unroll
            for (int k = 0; k < 5; ++k) wt[k] = swt1[(c * 5 + k) * 16 + o];
            #pragma unroll
            for (int ii = 0; ii < 9; ++ii) {
                int pos = sub + ii * 16;
                if (pos < 132) {
                    const float* sp = &sx[c][2 * pos];
                    float2 p0 = *(const float2*)(sp);
                    float2 p1 = *(const float2*)(sp + 2);
                    float2 p2 = *(const float2*)(sp + 4);
                    A0[ii] += wt[0]*p0.x + wt[1]*p0.y + wt[2]*p1.x + wt[3]*p1.y + wt[4]*p2.x;
                    A1[ii] += wt[0]*p0.y + wt[1]*p1.x + wt[2]*p1.y + wt[3]*p2.x + wt[4]*p2.y;
                }
            }
        }
        float bo = b1c[o];
        #pragma unroll
        for (int ii = 0; ii < 9; ++ii) {
            int pos = sub + ii * 16;
            if (pos < 132) {
                int t = t1lo + pos;
                float h = fmaxf(fmaxf(A0[ii], A1[ii]) + bo, 0.f);
                sh[o][pos] = ((unsigned)t < T1) ? h : 0.f;   // zero-pad outside T1
            }
        }
    }
    __syncthreads();

    // ---- conv2 + relu + pool2 + dis-scale -> nodes_b (bf16) ----
    int lane = tid & 63;
    int wv   = tid >> 6;
    int o    = lane & 31;
    int slot = lane >> 5;
    int ttl0 = wv * 16 + slot * 8;

    float acc[16];
    #pragma unroll
    for (int i = 0; i < 16; ++i) acc[i] = 0.f;

    #pragma unroll
    for (int c = 0; c < 16; ++c) {
        float wt[5];
        #pragma unroll
        for (int k = 0; k < 5; ++k) wt[k] = swt2[(c * 5 + k) * 32 + o];
        #pragma unroll
        for (int cb = 0; cb < 2; ++cb) {
            int Pb = 2 * ttl0 + 8 * cb;
            float4 i0 = *(const float4*)&sh[c][Pb];
            float4 i1 = *(const float4*)&sh[c][Pb + 4];
            float4 i2 = *(const float4*)&sh[c][Pb + 8];
            float in[12] = {i0.x,i0.y,i0.z,i0.w, i1.x,i1.y,i1.z,i1.w, i2.x,i2.y,i2.z,i2.w};
            #pragma unroll
            for (int q = 0; q < 8; ++q) {
                float s = acc[cb * 8 + q];
                #pragma unroll
                for (int k = 0; k < 5; ++k) s += wt[k] * in[q + k];
                acc[cb * 8 + q] = s;
            }
        }
    }

    float bi = b2c[o];
    int node0 = b * T2 + qt * 64 + ttl0;
    size_t nbase = (size_t)node0 * FEAT + o;
    #pragma unroll
    for (int cb = 0; cb < 2; ++cb)
        #pragma unroll
        for (int jj = 0; jj < 4; ++jj) {
            int node = node0 + cb * 4 + jj;
            float v = fmaxf(fmaxf(acc[cb*8+2*jj], acc[cb*8+2*jj+1]) + bi, 0.f);
            nodes_b[nbase + (size_t)(cb * 4 + jj) * FEAT] = f2bf(v * disv(cnt[node]));
        }
}

// ---------------- gather1 (bf16 in, fp32 out): aggN[d] = dis[d]*(nb[d] + Σ nb[src]) ----
__global__ __launch_bounds__(256) void k_gather1(const unsigned short* __restrict__ nodes_b,
                                                 const int* __restrict__ cnt,
                                                 const int* __restrict__ bucket,
                                                 float* __restrict__ aggN) {
    int t = blockIdx.x * 256 + threadIdx.x;
    int node = t >> 3;                    // 8 lanes per node, 8B bf16 each
    if (node >= NN) return;
    int lane = t & 7;
    int deg = cnt[node];
    const int* bk = bucket + node * CAP;
    const uint2* nb = (const uint2*)nodes_b;
    uint2 q = nb[(size_t)node * 8 + lane];
    float a0 = bf_lo(q.x), a1 = bf_hi(q.x), a2 = bf_lo(q.y), a3 = bf_hi(q.y);
    for (int j = 0; j < deg; ++j) {
        int s = bk[j];
        uint2 p = nb[(size_t)s * 8 + lane];
        a0 += bf_lo(p.x); a1 += bf_hi(p.x); a2 += bf_lo(p.y); a3 += bf_hi(p.y);
    }
    float dd = disv(deg);
    float4 r; r.x = a0 * dd; r.y = a1 * dd; r.z = a2 * dd; r.w = a3 * dd;
    ((float4*)aggN)[(size_t)node * 8 + lane] = r;
}

// ---------------- fused GCN transform: L1 fp32 GEMM + relu/bias + L2 MFMA bf16 ---------
// xws8[n] = fp8( (relu(aggN[n]@W1 + b1) @ W2) * dis[n] ), per 128-row block.
__global__ __launch_bounds__(256) void k_fused(const float* __restrict__ aggN,
                                               const float* __restrict__ w1,     // [32][128]
                                               const unsigned short* __restrict__ wt2, // [col][k] bf16
                                               const float* __restrict__ b1,
                                               const int* __restrict__ cnt,
                                               unsigned char* __restrict__ xws8) {
    __shared__ union {
        struct { float an[32][132]; float w1s[32][132]; } p1;   // 33 KB
        short sa[128 * 128];                                    // 32 KB, swizzled bf16 A
    } u;
    __shared__ short sW[128 * 128];   // 32 KB, [col][k] bf16 swizzled

    int tid = threadIdx.x;
    int rowBase = blockIdx.x * 128;

    // stage W2 (bf16 [col][k]) swizzled
    #pragma unroll
    for (int it = 0; it < 8; ++it) {
        int cr = it * 16 + (tid >> 4);
        int ck = tid & 15;
        uint4 v = *(const uint4*)(wt2 + cr * 128 + ck * 8);
        *(uint4*)&sW[cr * 128 + ((ck * 8) ^ ((cr & 7) << 3))] = v;
    }
    // stage aggN block (k-major) + W1
    {
        int ar = tid & 127;
        int half = tid >> 7;              // 0..1 -> k 0..15 / 16..31
        const float* arow = aggN + (size_t)(rowBase + ar) * FEAT + half * 16;
        #pragma unroll
        for (int q = 0; q < 4; ++q) {
            float4 va = *(const float4*)(arow + q * 4);
            int kb = half * 16 + q * 4;
            u.p1.an[kb + 0][ar] = va.x;
            u.p1.an[kb + 1][ar] = va.y;
            u.p1.an[kb + 2][ar] = va.z;
            u.p1.an[kb + 3][ar] = va.w;
        }
        #pragma unroll
        for (int it = 0; it < 4; ++it) {
            int i = tid + it * 256;       // 0..1023 float4s over [32][128]
            int k  = i >> 5;
            int c4 = (i & 31) * 4;
            *(float4*)&u.p1.w1s[k][c4] = *(const float4*)(w1 + k * HID + c4);
        }
    }
    __syncthreads();

    // ---- layer-1 fp32 GEMM: 8x8 per thread over [128][128] ----
    int tr = tid >> 4, tc = tid & 15;
    float acc[8][8];
    #pragma unroll
    for (int i = 0; i < 8; ++i)
        #pragma unroll
        for (int j = 0; j < 8; ++j) acc[i][j] = 0.f;

    #pragma unroll 8
    for (int k = 0; k < FEAT; ++k) {
        float4 a0 = *(const float4*)&u.p1.an[k][tr * 8];
        float4 a1 = *(const float4*)&u.p1.an[k][tr * 8 + 4];
        float4 b0 = *(const float4*)&u.p1.w1s[k][tc * 8];
        float4 b1v = *(const float4*)&u.p1.w1s[k][tc * 8 + 4];
        float av[8] = {a0.x, a0.y, a0.z, a0.w, a1.x, a1.y, a1.z, a1.w};
        float bv[8] = {b0.x, b0.y, b0.z, b0.w, b1v.x, b1v.y, b1v.z, b1v.w};
        #pragma unroll
        for (int i = 0; i < 8; ++i)
            #pragma unroll
            for (int j = 0; j < 8; ++j) acc[i][j] += av[i] * bv[j];
    }
    __syncthreads();   // phase-1 LDS dead; safe to overlay with sa

    // ---- bias + relu + bf16 pack into swizzled A-tile ----
    {
        float4 bb0 = *(const float4*)(b1 + tc * 8);
        float4 bb1 = *(const float4*)(b1 + tc * 8 + 4);
        float bv[8] = {bb0.x, bb0.y, bb0.z, bb0.w, bb1.x, bb1.y, bb1.z, bb1.w};
        #pragma unroll
        for (int i = 0; i < 8; ++i) {
            int row = tr * 8 + i;
            unsigned short us[8];
            #pragma unroll
            for (int j = 0; j < 8; ++j) us[j] = f2bf(fmaxf(acc[i][j] + bv[j], 0.f));
            uint4 pv;
            pv.x = (unsigned)us[0] | ((unsigned)us[1] << 16);
            pv.y = (unsigned)us[2] | ((unsigned)us[3] << 16);
            pv.z = (unsigned)us[4] | ((unsigned)us[5] << 16);
            pv.w = (unsigned)us[6] | ((unsigned)us[7] << 16);
            *(uint4*)&u.sa[row * 128 + ((tc * 8) ^ ((row & 7) << 3))] = pv;
        }
    }
    __syncthreads();

    // ---- layer-2 MFMA bf16 ----
    int lane = tid & 63;
    int wv   = tid >> 6;
    int lrow = lane & 15;
    int kg   = lane >> 4;                // k-group 0..3

    f32x4 zero = {0.f, 0.f, 0.f, 0.f};
    f32x4 macc[2][8];
    #pragma unroll
    for (int rt = 0; rt < 2; ++rt)
        #pragma unroll
        for (int ct = 0; ct < 8; ++ct) macc[rt][ct] = zero;

    #pragma unroll
    for (int ks = 0; ks < 4; ++ks) {
        int kb8 = ks * 4 + kg;           // 8-bf16 chunk index along k
        bf16x8 af[2];
        #pragma unroll
        for (int rt = 0; rt < 2; ++rt) {
            int r = wv * 32 + rt * 16 + lrow;
            af[rt] = *(const bf16x8*)&u.sa[r * 128 + ((kb8 * 8) ^ ((r & 7) << 3))];
        }
        #pragma unroll
        for (int ct = 0; ct < 8; ++ct) {
            int c = ct * 16 + lrow;
            bf16x8 bfr = *(const bf16x8*)&sW[c * 128 + ((kb8 * 8) ^ ((c & 7) << 3))];
            macc[0][ct] = __builtin_amdgcn_mfma_f32_16x16x32_bf16(af[0], bfr, macc[0][ct], 0, 0, 0);
            macc[1][ct] = __builtin_amdgcn_mfma_f32_16x16x32_bf16(af[1], bfr, macc[1][ct], 0, 0, 0);
        }
    }

    // epilogue: D layout col=lane&15, row=(lane>>4)*4+reg; store fp8 bytes
    #pragma unroll
    for (int rt = 0; rt < 2; ++rt) {
        int r0 = rowBase + wv * 32 + rt * 16 + kg * 4;
        #pragma unroll
        for (int q = 0; q < 4; ++q) {
            int grow = r0 + q;
            float d = disv(cnt[grow]);
            unsigned char* op = xws8 + (size_t)grow * HID + lrow;
            #pragma unroll
            for (int ct = 0; ct < 8; ++ct)
                op[ct * 16] = f2fp8(macc[rt][ct][q] * d);
        }
    }
}

// ---------------- gather2 (fp8 rows) + fused pool: partial[blk][f] = Σ relu(agg2+b2) ---
__global__ __launch_bounds__(256) void k_gather2(const unsigned char* __restrict__ xws8,
                                                 const int* __restrict__ cnt,
                                                 const int* __restrict__ bucket,
                                                 const float* __restrict__ b2,
                                                 float* __restrict__ partial) {
    __shared__ float sred[32][133];
    int t = blockIdx.x * 256 + threadIdx.x;
    int node = t >> 3;                    // 8 lanes per node (16 fp8 = 16B each)
    int lane = t & 7;
    int nloc = threadIdx.x >> 3;
    int deg = cnt[node];
    const int* bk = bucket + node * CAP;
    const uint4* xv = (const uint4*)xws8;      // row = 8 uint4
    float a[16];
    {
        uint4 q = xv[(size_t)node * 8 + lane];
        fp8x4_to_f32(q.x, a + 0);
        fp8x4_to_f32(q.y, a + 4);
        fp8x4_to_f32(q.z, a + 8);
        fp8x4_to_f32(q.w, a + 12);
    }
    for (int j = 0; j < deg; ++j) {
        int s = bk[j];
        uint4 p = xv[(size_t)s * 8 + lane];
        fp8x4_acc_f32(p.x, a + 0);
        fp8x4_acc_f32(p.y, a + 4);
        fp8x4_acc_f32(p.z, a + 8);
        fp8x4_acc_f32(p.w, a + 12);
    }
    float dd = disv(deg);
    float* sp = &sred[nloc][lane * 16];
    const float* bp = b2 + lane * 16;
    #pragma unroll
    for (int i = 0; i < 16; ++i)
        sp[i] = fmaxf(a[i] * dd + bp[i], 0.f);
    __syncthreads();
    int f = threadIdx.x;
    if (f < 128) {
        float s = 0.f;
        #pragma unroll
        for (int n = 0; n < 32; ++n) s += sred[n][f];
        partial[(size_t)blockIdx.x * HID + f] = s;
    }
}

// ---------------- classifier: out[b][f] = mean @ cls_w + cls_b -------------------------
__global__ __launch_bounds__(128) void k_cls(const float* __restrict__ partial,
                                             const float* __restrict__ clsw,
                                             const float* __restrict__ clsb,
                                             float* __restrict__ out) {
    __shared__ float pooled[HID];
    int b = blockIdx.x;
    int f = threadIdx.x;
    const float* p = partial + (size_t)b * 16 * HID + f;
    float s = 0.f;
    #pragma unroll 8
    for (int c = 0; c < 16; ++c) s += p[c * HID];
    pooled[f] = s;
    __syncthreads();
    if (f < OUTC) {
        float acc = 0.f;
        #pragma unroll 8
        for (int k = 0; k < HID; ++k) acc += pooled[k] * clsw[k * OUTC + f];
        out[b * OUTC + f] = acc * (1.0f / (float)T2) + clsb[f];
    }
}

extern "C" void kernel_launch(void* const* d_in, const int* in_sizes, int n_in,
                              void* d_out, int out_size, void* d_ws, size_t ws_size,
                              hipStream_t stream) {
    const float* x    = (const float*)d_in[0];
    const int*   ei   = (const int*)d_in[1];
    const float* c1w  = (const float*)d_in[2];
    const float* c1b  = (const float*)d_in[3];
    const float* c2w  = (const float*)d_in[4];
    const float* c2b  = (const float*)d_in[5];
    const float* g1w  = (const float*)d_in[6];
    const float* g1b  = (const float*)d_in[7];
    const float* g2w  = (const float*)d_in[8];
    const float* g2b  = (const float*)d_in[9];
    const float* clsw = (const float*)d_in[10];
    const float* clsb = (const float*)d_in[11];
    float* out = (float*)d_out;

    float* ws = (float*)d_ws;
    float* aggN     = ws;                                      // [0, 2097152)  N*32 fp32
    float* partial  = ws + 2097152;                            // [2097152, 2359296)
    unsigned short* wt2 = (unsigned short*)(ws + 2359296);     // [2359296, 2367488)
    unsigned short* nodes_b = (unsigned short*)(ws + 2367488); // [2367488, 3416064)
    unsigned char* xws8 = (unsigned char*)(ws + 3416064);      // [3416064, 5513216)
    int* cnt        = (int*)(ws + 5513216);                    // [5513216, 5578752)
    int* bucket     = (int*)(ws + 5578752);                    // [5578752, 9773056)  NN*CAP
    // total ~39.1 MB

    // single-pass bucket CSR build (cnt zeroed + W2 prep, then deg+fill fused)
    k_zw   <<<64, 256, 0, stream>>>((int4*)cnt, g2w, wt2);
    k_fillB<<<EE / 256, 256, 0, stream>>>(ei, cnt, bucket);

    // fused temporal conv stack (h1 LDS-resident), bf16 pre-scaled nodes
    k_conv12<<<BB * 8, 256, 0, stream>>>(x, c1w, c1b, c2w, c2b, cnt, nodes_b);

    // GCN layer 1 aggregation (standalone, high occupancy, bf16 rows)
    k_gather1<<<(NN * 8) / 256, 256, 0, stream>>>(nodes_b, cnt, bucket, aggN);

    // fused GCN transform: L1 fp32 + relu/bias + L2 MFMA bf16, fp8 output rows
    k_fused<<<NN / 128, 256, 0, stream>>>(aggN, g1w, wt2, g1b, cnt, xws8);

    // layer-2 aggregation (fp8 rows) with fused mean-pool partials
    k_gather2<<<(NN * 8) / 256, 256, 0, stream>>>(xws8, cnt, bucket, g2b, partial);

    // classifier
    k_cls<<<BB, 128, 0, stream>>>(partial, clsw, clsb, out);
}